// Round 1
// baseline (173.958 us; speedup 1.0000x reference)
//
#include <hip/hip_runtime.h>
#include <math.h>

// ws layout (floats)
#define WS_H    0
#define WS_U    128
#define WS_W2   256
#define WS_QBK  384
#define WS_S0   385
#define WS_S1   386
#define WS_ACC  512      // [16][128]
#define WS_ESUM 2560     // [16]

__device__ __forceinline__ float frcp_(float x){ return __builtin_amdgcn_rcpf(x); }
__device__ __forceinline__ float fsig_(float x){ return frcp_(1.f + __expf(-x)); }
__device__ __forceinline__ float ftanh_(float x){ return 1.f - 2.f*frcp_(1.f + __expf(2.f*x)); }

// ---------------- K1: serial target LSTM + precomputes + ws init ----------------
__global__ __launch_bounds__(512) void k1_target(
    const float* __restrict__ target,
    const float* __restrict__ W_ih, const float* __restrict__ W_hh,
    const float* __restrict__ b_ih, const float* __restrict__ b_hh,
    const float* __restrict__ Wq,  const float* __restrict__ bq,
    const float* __restrict__ Wk,  const float* __restrict__ bk,
    const float* __restrict__ Wv,  const float* __restrict__ bv,
    const float* __restrict__ Wo,  const float* __restrict__ bo,
    const float* __restrict__ Wgq, const float* __restrict__ bgq,
    const float* __restrict__ Wgk, const float* __restrict__ bgk,
    float* __restrict__ ws)
{
    __shared__ __align__(16) float h_s[128];
    __shared__ float g_s[512];
    __shared__ __align__(16) float q_s[128], qg_s[128], u_s[128], ug_s[128], w1_s[128], w2_s[128];
    __shared__ float red[384];
    const int tid = threadIdx.x;

    // zero global accumulators (ws is poisoned 0xAA before every launch)
    for (int i = tid; i < 16*128 + 16; i += 512) ws[WS_ACC + i] = 0.f;
    if (tid < 128) h_s[tid] = 0.f;

    // per-thread gate row (tid in [0,512))
    float wih[8];
    #pragma unroll
    for (int k = 0; k < 8; ++k) wih[k] = W_ih[tid*8 + k];
    const float bsum = b_ih[tid] + b_hh[tid];
    float4 whh[32];   // register-resident W_hh row (512B/lane)
    {
        const float4* w4 = (const float4*)(W_hh + tid*128);
        #pragma unroll
        for (int m = 0; m < 32; ++m) whh[m] = w4[m];
    }
    float c = 0.f;
    __syncthreads();

    for (int t = 0; t < 15; ++t) {
        float g = bsum;
        #pragma unroll
        for (int k = 0; k < 8; ++k) g += target[t*8 + k] * wih[k];
        const float4* h4 = (const float4*)h_s;
        float acc = 0.f;
        #pragma unroll
        for (int m = 0; m < 32; ++m) {
            float4 hv = h4[m];
            acc += whh[m].x*hv.x + whh[m].y*hv.y + whh[m].z*hv.z + whh[m].w*hv.w;
        }
        g += acc;
        g_s[tid] = g;
        __syncthreads();
        if (tid < 128) {
            float ig = fsig_(g_s[tid]);
            float fg = fsig_(g_s[tid+128]);
            float gg = ftanh_(g_s[tid+256]);
            float og = fsig_(g_s[tid+384]);
            c = fg*c + ig*gg;
            h_s[tid] = og*ftanh_(c);
        }
        __syncthreads();
    }

    // q = Wq h + bq ; qg = Wgq h + bgq
    if (tid < 128) {
        const float4* wq4  = (const float4*)(Wq  + tid*128);
        const float4* wgq4 = (const float4*)(Wgq + tid*128);
        const float4* h4 = (const float4*)h_s;
        float a1 = bq[tid], a2 = bgq[tid];
        #pragma unroll
        for (int m = 0; m < 32; ++m) {
            float4 hv = h4[m]; float4 wa = wq4[m]; float4 wb = wgq4[m];
            a1 += wa.x*hv.x + wa.y*hv.y + wa.z*hv.z + wa.w*hv.w;
            a2 += wb.x*hv.x + wb.y*hv.y + wb.z*hv.z + wb.w*hv.w;
        }
        q_s[tid] = a1; qg_s[tid] = a2;
    }
    __syncthreads();
    // u = Wk^T q ; ug = Wgk^T qg   (coalesced over j)
    if (tid < 128) {
        float a1 = 0.f, a2 = 0.f;
        for (int j = 0; j < 128; ++j) {
            a1 += q_s[j]  * Wk[j*128 + tid];
            a2 += qg_s[j] * Wgk[j*128 + tid];
        }
        u_s[tid] = a1; ug_s[tid] = a2;
    }
    __syncthreads();
    // w1 = Wo^T ug
    if (tid < 128) {
        float a = 0.f;
        for (int j = 0; j < 128; ++j) a += ug_s[j] * Wo[j*128 + tid];
        w1_s[tid] = a;
    }
    __syncthreads();
    // w2 = Wv^T w1 ; scalar partials
    if (tid < 128) {
        float a = 0.f;
        for (int j = 0; j < 128; ++j) a += w1_s[j] * Wv[j*128 + tid];
        w2_s[tid] = a;
        red[tid]     = q_s[tid]*bk[tid];
        red[128+tid] = qg_s[tid]*bgk[tid];
        red[256+tid] = w1_s[tid]*bv[tid] + ug_s[tid]*bo[tid];
    }
    __syncthreads();
    if (tid == 0) {
        float qbk = 0.f, s0 = 0.f, sx = 0.f;
        for (int j = 0; j < 128; ++j) { qbk += red[j]; s0 += red[128+j]; sx += red[256+j]; }
        ws[WS_QBK] = qbk; ws[WS_S0] = s0; ws[WS_S1] = sx + s0;
    }
    if (tid < 128) {
        ws[WS_H + tid]  = h_s[tid];
        ws[WS_U + tid]  = u_s[tid];
        ws[WS_W2 + tid] = w2_s[tid];
    }
}

// ---------------- K3: neighbor pass (t=14 only), wave-per-neighbor ----------------
#define K3_BLOCKS 128
__global__ __launch_bounds__(256) void k3_neighbors(
    const float* __restrict__ target, const float* __restrict__ others,
    const int* __restrict__ mask, const float* __restrict__ W_ih,
    const float* __restrict__ b_ih, const float* __restrict__ b_hh,
    float* __restrict__ ws)
{
    __shared__ float accs[16*128];
    __shared__ float esums[16];
    __shared__ int used[16];
    const int tid  = threadIdx.x;
    const int lane = tid & 63;
    const int wave = tid >> 6;

    for (int i = tid; i < 2048; i += 256) accs[i] = 0.f;
    if (tid < 16) { esums[tid] = 0.f; used[tid] = 0; }

    const int d0 = lane, d1 = lane + 64;
    // register-resident W_ih rows for gates i (rows d), g (256+d), o (384+d)
    float wi0[8], wg0[8], wo0[8], wi1[8], wg1[8], wo1[8];
    #pragma unroll
    for (int k = 0; k < 8; ++k) {
        wi0[k] = W_ih[d0*8+k];        wi1[k] = W_ih[d1*8+k];
        wg0[k] = W_ih[(256+d0)*8+k];  wg1[k] = W_ih[(256+d1)*8+k];
        wo0[k] = W_ih[(384+d0)*8+k];  wo1[k] = W_ih[(384+d1)*8+k];
    }
    const float bi0 = b_ih[d0]+b_hh[d0],         bi1 = b_ih[d1]+b_hh[d1];
    const float bg0 = b_ih[256+d0]+b_hh[256+d0], bg1 = b_ih[256+d1]+b_hh[256+d1];
    const float bo0 = b_ih[384+d0]+b_hh[384+d0], bo1 = b_ih[384+d1]+b_hh[384+d1];
    const float u0 = ws[WS_U + d0], u1 = ws[WS_U + d1];
    const float qbk = ws[WS_QBK];
    const float tx0 = target[14*8 + 0], tx1 = target[14*8 + 1];
    const float* __restrict__ oth  = others + 14*16384*8;
    const int*   __restrict__ mk14 = mask   + 14*16384;
    const float scale = 0.08838834764831845f;  // 1/sqrt(128)
    __syncthreads();

    const int gw = blockIdx.x*4 + wave;                   // [0,512)
    const int nper = 16384 / (K3_BLOCKS*4);               // 32
    for (int n = gw*nper; n < gw*nper + nper; ++n) {
        const int mk = mk14[n];
        const float4 xa = ((const float4*)oth)[n*2];
        const float4 xb = ((const float4*)oth)[n*2 + 1];
        const float r0 = xa.x - tx0, r1 = xa.y - tx1;
        bool ok = (fabsf(r0) <= 2.f) & (fabsf(r1) <= 2.f) & (mk != 0);
        const int cx = (int)truncf(r0) + 2;               // cw = ch = 1.0 exactly
        const int cy = (int)truncf(r1) + 2;
        ok = ok & (cx >= 0) & (cx < 4) & (cy >= 0) & (cy < 4);
        if (!ok) continue;                                // wave-uniform
        const int cell = cy*4 + cx;
        float x[8] = {xa.x, xa.y, xa.z, xa.w, xb.x, xb.y, xb.z, xb.w};
        // dim d0
        float gi = bi0, gg = bg0, go = bo0;
        #pragma unroll
        for (int k = 0; k < 8; ++k) { gi += x[k]*wi0[k]; gg += x[k]*wg0[k]; go += x[k]*wo0[k]; }
        const float ho0 = fsig_(go) * ftanh_(fsig_(gi) * ftanh_(gg));
        // dim d1
        gi = bi1; gg = bg1; go = bo1;
        #pragma unroll
        for (int k = 0; k < 8; ++k) { gi += x[k]*wi1[k]; gg += x[k]*wg1[k]; go += x[k]*wo1[k]; }
        const float ho1 = fsig_(go) * ftanh_(fsig_(gi) * ftanh_(gg));
        // score dot: wave butterfly reduce
        float p = u0*ho0 + u1*ho1;
        #pragma unroll
        for (int s = 1; s < 64; s <<= 1) p += __shfl_xor(p, s, 64);
        const float sc = (p + qbk) * scale;
        const float e = __expf(sc);   // per-cell max subtraction is softmax-invariant; |sc| << 1
        atomicAdd(&accs[cell*128 + d0], e*ho0);
        atomicAdd(&accs[cell*128 + d1], e*ho1);
        if (lane == 0) { atomicAdd(&esums[cell], e); used[cell] = 1; }
    }
    __syncthreads();
    for (int i = tid; i < 2048; i += 256) {
        const int c = i >> 7;
        if (used[c]) {
            const float v = accs[i];
            if (v != 0.f) atomicAdd(&ws[WS_ACC + i], v);
        }
    }
    if (tid < 16 && used[tid]) atomicAdd(&ws[WS_ESUM + tid], esums[tid]);
}

// ---------------- K4: finale (grid attention folded to matvecs) ----------------
__global__ __launch_bounds__(128) void k4_finale(
    const float* __restrict__ Wv, const float* __restrict__ bv,
    const float* __restrict__ Wo, const float* __restrict__ bo,
    const float* __restrict__ Wgv, const float* __restrict__ bgv,
    const float* __restrict__ Wc, const float* __restrict__ bc,
    const float* __restrict__ ws, float* __restrict__ out)
{
    __shared__ __align__(16) float avg[16*128];
    __shared__ float gw_s[16];
    __shared__ float s_sh[16];
    __shared__ __align__(16) float mavg[128], t_s[128], mix[128], comb[128];
    __shared__ float alpha_s;
    const int tid = threadIdx.x;
    const float scale = 0.08838834764831845f;

    #pragma unroll
    for (int c = 0; c < 16; ++c) {
        const float es = ws[WS_ESUM + c];
        avg[c*128 + tid] = (es > 0.f) ? ws[WS_ACC + c*128 + tid] / es : 0.f;
    }
    __syncthreads();
    if (tid < 16) {
        const float es = ws[WS_ESUM + tid];
        float s;
        if (es > 0.f) {
            s = ws[WS_S1];
            for (int m = 0; m < 128; ++m) s += ws[WS_W2 + m] * avg[tid*128 + m];
        } else {
            s = ws[WS_S0];
        }
        s_sh[tid] = s * scale;
    }
    __syncthreads();
    if (tid == 0) {
        float mx = -1e30f;
        #pragma unroll
        for (int c = 0; c < 16; ++c) mx = fmaxf(mx, s_sh[c]);
        float e[16]; float den = 0.f;
        #pragma unroll
        for (int c = 0; c < 16; ++c) { e[c] = __expf(s_sh[c] - mx); den += e[c]; }
        float a = 0.f;
        #pragma unroll
        for (int c = 0; c < 16; ++c) {
            const float g = e[c] / den;
            gw_s[c] = g;
            if (ws[WS_ESUM + c] > 0.f) a += g;
        }
        alpha_s = a;
    }
    __syncthreads();
    {
        float a = 0.f;
        #pragma unroll
        for (int c = 0; c < 16; ++c) a += gw_s[c] * avg[c*128 + tid];
        mavg[tid] = a;
    }
    __syncthreads();
    const float alpha = alpha_s;
    {   // t = Wv mavg + alpha*bv
        float a = alpha * bv[tid];
        const float4* w = (const float4*)(Wv + tid*128);
        const float4* v = (const float4*)mavg;
        #pragma unroll
        for (int m = 0; m < 32; ++m) { float4 ww = w[m], vv = v[m];
            a += ww.x*vv.x + ww.y*vv.y + ww.z*vv.z + ww.w*vv.w; }
        t_s[tid] = a;
    }
    __syncthreads();
    {   // mix = Wo t + alpha*bo
        float a = alpha * bo[tid];
        const float4* w = (const float4*)(Wo + tid*128);
        const float4* v = (const float4*)t_s;
        #pragma unroll
        for (int m = 0; m < 32; ++m) { float4 ww = w[m], vv = v[m];
            a += ww.x*vv.x + ww.y*vv.y + ww.z*vv.z + ww.w*vv.w; }
        mix[tid] = a;
    }
    __syncthreads();
    {   // ctx = Wgv mix + bgv ; combined = h + ctx
        float a = bgv[tid];
        const float4* w = (const float4*)(Wgv + tid*128);
        const float4* v = (const float4*)mix;
        #pragma unroll
        for (int m = 0; m < 32; ++m) { float4 ww = w[m], vv = v[m];
            a += ww.x*vv.x + ww.y*vv.y + ww.z*vv.z + ww.w*vv.w; }
        comb[tid] = ws[WS_H + tid] + a;
    }
    __syncthreads();
    if (tid < 2) {
        float a = bc[tid];
        for (int m = 0; m < 128; ++m) a += Wc[tid*128 + m] * comb[m];
        out[tid] = a;
    }
}

extern "C" void kernel_launch(void* const* d_in, const int* in_sizes, int n_in,
                              void* d_out, int out_size, void* d_ws, size_t ws_size,
                              hipStream_t stream) {
    (void)in_sizes; (void)n_in; (void)out_size; (void)ws_size;
    const float* target = (const float*)d_in[0];
    const float* others = (const float*)d_in[1];
    const int*   mask   = (const int*)d_in[2];
    const float* W_ih = (const float*)d_in[3];
    const float* W_hh = (const float*)d_in[4];
    const float* b_ih = (const float*)d_in[5];
    const float* b_hh = (const float*)d_in[6];
    const float* Wq  = (const float*)d_in[7];  const float* bq  = (const float*)d_in[8];
    const float* Wk  = (const float*)d_in[9];  const float* bk  = (const float*)d_in[10];
    const float* Wv  = (const float*)d_in[11]; const float* bv  = (const float*)d_in[12];
    const float* Wo  = (const float*)d_in[13]; const float* bo  = (const float*)d_in[14];
    const float* Wgq = (const float*)d_in[15]; const float* bgq = (const float*)d_in[16];
    const float* Wgk = (const float*)d_in[17]; const float* bgk = (const float*)d_in[18];
    const float* Wgv = (const float*)d_in[19]; const float* bgv = (const float*)d_in[20];
    const float* Wc  = (const float*)d_in[21]; const float* bc  = (const float*)d_in[22];
    float* ws  = (float*)d_ws;
    float* out = (float*)d_out;

    k1_target<<<dim3(1), dim3(512), 0, stream>>>(target, W_ih, W_hh, b_ih, b_hh,
        Wq, bq, Wk, bk, Wv, bv, Wo, bo, Wgq, bgq, Wgk, bgk, ws);
    k3_neighbors<<<dim3(K3_BLOCKS), dim3(256), 0, stream>>>(target, others, mask,
        W_ih, b_ih, b_hh, ws);
    k4_finale<<<dim3(1), dim3(128), 0, stream>>>(Wv, bv, Wo, bo, Wgv, bgv, Wc, bc, ws, out);
}